// Round 1
// baseline (620.317 us; speedup 1.0000x reference)
//
#include <hip/hip_runtime.h>

#define T_ 512
#define K_ 128
#define B_ 256

// One block per batch. 512 threads = 8 waves.
// Waves 0-3: forward (logsumexp) over columns j, 2-way split of the i-loop.
// Waves 4-7: viterbi (max/argmax)  over columns j, 2-way split of the i-loop.
// Thread (j, c) holds transitions[c*64 .. c*64+63][j] in 64 registers
// (exp() of it for forward). alpha/viterbi vectors double-buffered in LDS,
// one __syncthreads per time step. Backpointers live in LDS (uint8, 64KB).
__global__ __launch_bounds__(512, 2) void crf_main(
    const float* __restrict__ emissions,
    const int* __restrict__ tag_ids,
    const int* __restrict__ lengths,
    const float* __restrict__ transitions,
    float* __restrict__ out,
    float* __restrict__ ws_ll,
    int* __restrict__ ws_cnt)
{
    __shared__ unsigned char bpLDS[T_ * K_];            // 64 KB backpointers
    __shared__ __align__(16) float eaBuf[2][K_];        // exp(alpha - S), double buffered
    __shared__ __align__(16) float vaBuf[2][K_];        // viterbi scores, double buffered
    __shared__ __align__(16) float wmax[2][4];          // per-fwd-wave max of alpha
    __shared__ float redLDS[8];                         // score partials (preserved through loop)
    __shared__ int   redILDS[8];                        // accuracy-count partials
    __shared__ unsigned char decLDS[T_];                // decoded chain
    __shared__ int ltagLDS;

    const int b   = blockIdx.x;
    const int tid = threadIdx.x;
    const int len = lengths[b];
    const float* emB = emissions + (size_t)b * T_ * K_;
    const int*  tagB = tag_ids + b * T_;

    // ---------------- sequence score (unary + binary), one t per thread ----------------
    {
        int t = tid;                    // blockDim == T_
        float s = 0.f;
        if (t < len) {
            int tg = tagB[t];
            s = emB[t * K_ + tg];
            if (t >= 1) s += transitions[tagB[t - 1] * K_ + tg];
        }
        #pragma unroll
        for (int m = 1; m < 64; m <<= 1) s += __shfl_xor(s, m);
        if ((tid & 63) == 0) redLDS[tid >> 6] = s;
    }

    const int role = tid >> 8;          // 0 = forward, 1 = viterbi
    const int lin  = tid & 255;
    const int j = lin >> 1;             // column 0..127
    const int c = lin & 1;              // which half of the i-range

    // ---------------- per-thread transition column (registers) ----------------
    float tbl[64];
    if (role == 0) {
        #pragma unroll
        for (int k = 0; k < 64; ++k)
            tbl[k] = __expf(transitions[(c * 64 + k) * K_ + j]);
    } else {
        #pragma unroll
        for (int k = 0; k < 64; ++k)
            tbl[k] = transitions[(c * 64 + k) * K_ + j];
    }

    // ---------------- init t = 0 ----------------
    float e0 = emB[j];
    if (role == 0) {
        if (c == 0) eaBuf[0][j] = __expf(e0);           // offset S0 = 0
        float wm = e0;
        #pragma unroll
        for (int m = 1; m < 64; m <<= 1) wm = fmaxf(wm, __shfl_xor(wm, m));
        if ((tid & 63) == 0) wmax[0][tid >> 6] = wm;
    } else {
        if (c == 0) vaBuf[0][j] = e0;
    }
    __syncthreads();

    // ---------------- main recurrence ----------------
    int cur = 0;
    float Sprev = 0.f;                                  // offset of current ea buffer
    for (int t = 1; t < len; ++t) {
        const float* em = emB + t * K_;
        if (role == 0) {
            float4 wv = *(const float4*)&wmax[cur][0];
            float Scur = fmaxf(fmaxf(wv.x, wv.y), fmaxf(wv.z, wv.w)); // max alpha_{t-1}
            float emit = em[j];
            const float* ea = &eaBuf[cur][c * 64];
            float a0 = 0.f, a1 = 0.f, a2 = 0.f, a3 = 0.f;
            #pragma unroll
            for (int k = 0; k < 16; ++k) {
                float4 e4 = *(const float4*)(ea + 4 * k);
                a0 = fmaf(e4.x, tbl[4 * k + 0], a0);
                a1 = fmaf(e4.y, tbl[4 * k + 1], a1);
                a2 = fmaf(e4.z, tbl[4 * k + 2], a2);
                a3 = fmaf(e4.w, tbl[4 * k + 3], a3);
            }
            float dot = (a0 + a1) + (a2 + a3);
            dot += __shfl_xor(dot, 1);                  // combine the two i-halves
            float anew = __logf(dot) + Sprev + emit;
            if (c == 0) eaBuf[cur ^ 1][j] = __expf(anew - Scur);
            float wm = anew;
            #pragma unroll
            for (int m = 1; m < 64; m <<= 1) wm = fmaxf(wm, __shfl_xor(wm, m));
            if ((lin & 63) == 0) wmax[cur ^ 1][lin >> 6] = wm;
            Sprev = Scur;
        } else {
            float emit = em[j];
            const float* va = &vaBuf[cur][c * 64];
            float mB = -3.4028235e38f;
            int arg = 0;
            #pragma unroll
            for (int k = 0; k < 16; ++k) {              // ascending i, strict > = first-max-wins
                float4 v4 = *(const float4*)(va + 4 * k);
                float s0 = v4.x + tbl[4 * k + 0]; if (s0 > mB) { mB = s0; arg = 4 * k + 0; }
                float s1 = v4.y + tbl[4 * k + 1]; if (s1 > mB) { mB = s1; arg = 4 * k + 1; }
                float s2 = v4.z + tbl[4 * k + 2]; if (s2 > mB) { mB = s2; arg = 4 * k + 2; }
                float s3 = v4.w + tbl[4 * k + 3]; if (s3 > mB) { mB = s3; arg = 4 * k + 3; }
            }
            arg += c * 64;
            float om = __shfl_xor(mB, 1);
            int   oa = __shfl_xor(arg, 1);
            // low-i half wins ties
            float mLow  = c ? om : mB;   int aLow  = c ? oa : arg;
            float mHigh = c ? mB : om;   int aHigh = c ? arg : oa;
            float mF; int aF;
            if (mHigh > mLow) { mF = mHigh; aF = aHigh; } else { mF = mLow; aF = aLow; }
            if (c == 0) {
                vaBuf[cur ^ 1][j] = mF + emit;
                bpLDS[t * K_ + j] = (unsigned char)aF;
            }
        }
        cur ^= 1;
        __syncthreads();
    }

    // ---------------- logZ (forward wave 0) ----------------
    float logZv = 0.f;
    if (tid < 64) {
        float s = eaBuf[cur][tid] + eaBuf[cur][tid + 64];
        #pragma unroll
        for (int m = 1; m < 64; m <<= 1) s += __shfl_xor(s, m);
        logZv = Sprev + __logf(s);                      // valid in lane 0 (tid 0)
    }

    // ---------------- last tag: argmax_j v_final (first-max-wins) ----------------
    if (tid >= 256 && tid < 320) {
        int l = tid - 256;
        float m = vaBuf[cur][l]; int a = l;
        float v2 = vaBuf[cur][l + 64];
        if (v2 > m) { m = v2; a = l + 64; }
        #pragma unroll
        for (int sft = 1; sft < 64; sft <<= 1) {
            float om = __shfl_xor(m, sft);
            int   oa = __shfl_xor(a, sft);
            if (om > m || (om == m && oa < a)) { m = om; a = oa; }
        }
        if (l == 0) ltagLDS = a;
    }
    __syncthreads();

    // ---------------- backtrace (serial chain through LDS) ----------------
    if (tid == 0) {
        int tg = ltagLDS;
        for (int t = T_ - 1; t >= 1; --t) {
            decLDS[t] = (unsigned char)tg;
            if (t < len) tg = bpLDS[t * K_ + tg];       // identity bp for t >= len
        }
        decLDS[0] = (unsigned char)tg;
    }
    __syncthreads();

    // ---------------- decoded write + accuracy count ----------------
    {
        int t = tid;
        int dv = decLDS[t];
        out[1 + b * T_ + t] = (float)dv;
        int good = (t < len && tagB[t] == dv) ? 1 : 0;
        #pragma unroll
        for (int m = 1; m < 64; m <<= 1) good += __shfl_xor(good, m);
        if ((tid & 63) == 0) redILDS[tid >> 6] = good;
    }
    __syncthreads();

    if (tid == 0) {
        float sc = 0.f; int cnt = 0;
        #pragma unroll
        for (int w = 0; w < 8; ++w) { sc += redLDS[w]; cnt += redILDS[w]; }
        ws_ll[b]  = sc - logZv;                         // log-likelihood of batch b
        ws_cnt[b] = cnt;
    }
}

// Final reduction: loss = -mean(ll), accuracy = sum(correct)/sum(len)
__global__ void crf_final(const float* __restrict__ ws_ll,
                          const int* __restrict__ ws_cnt,
                          const int* __restrict__ lengths,
                          float* __restrict__ out)
{
    __shared__ float sll[4];
    __shared__ int scnt[4], slen[4];
    int tid = threadIdx.x;                              // blockDim == B_ == 256
    float ll = ws_ll[tid];
    int   cn = ws_cnt[tid];
    int   L  = lengths[tid];
    #pragma unroll
    for (int m = 1; m < 64; m <<= 1) {
        ll += __shfl_xor(ll, m);
        cn += __shfl_xor(cn, m);
        L  += __shfl_xor(L, m);
    }
    if ((tid & 63) == 0) { sll[tid >> 6] = ll; scnt[tid >> 6] = cn; slen[tid >> 6] = L; }
    __syncthreads();
    if (tid == 0) {
        float llS = sll[0] + sll[1] + sll[2] + sll[3];
        int   cS  = scnt[0] + scnt[1] + scnt[2] + scnt[3];
        int   LS  = slen[0] + slen[1] + slen[2] + slen[3];
        out[0] = -llS / (float)B_;
        out[1 + B_ * T_] = (float)cS / (float)LS;
    }
}

extern "C" void kernel_launch(void* const* d_in, const int* in_sizes, int n_in,
                              void* d_out, int out_size, void* d_ws, size_t ws_size,
                              hipStream_t stream) {
    const float* emissions   = (const float*)d_in[0];
    const int*   tag_ids     = (const int*)d_in[1];
    const int*   lengths     = (const int*)d_in[2];
    const float* transitions = (const float*)d_in[3];
    float* out = (float*)d_out;

    float* ws_ll  = (float*)d_ws;
    int*   ws_cnt = (int*)((char*)d_ws + B_ * sizeof(float));

    crf_main<<<B_, 512, 0, stream>>>(emissions, tag_ids, lengths, transitions,
                                     out, ws_ll, ws_cnt);
    crf_final<<<1, B_, 0, stream>>>(ws_ll, ws_cnt, lengths, out);
}